// Round 2
// baseline (96.648 us; speedup 1.0000x reference)
//
#include <hip/hip_runtime.h>

#define VPR 10  // float4 blocks per row (X_DIM=40)

typedef float v4f __attribute__((ext_vector_type(4)));

__global__ __launch_bounds__(256) void lorenz96_feats_kernel(
    const float4* __restrict__ u4,
    const float* __restrict__ coeff,
    v4f* __restrict__ out4) {
    // grid sized exactly: 2,621,440 threads, no tail check needed
    unsigned int v = blockIdx.x * 256u + threadIdx.x;

    // row r = v / 10, float4-block-within-row p4 = v % 10
    unsigned int r  = v / VPR;
    unsigned int p4 = v - r * VPR;

    const float4* row = u4 + (size_t)r * VPR;
    float4 cen = row[p4];
    float4 prv = row[p4 == 0       ? VPR - 1 : p4 - 1];
    float4 nxt = row[p4 == VPR - 1 ? 0       : p4 + 1];

    // a[j] = u[row, (4*p4 - 2 + j) mod 40], j = 0..7
    float a[8];
    a[0] = prv.z; a[1] = prv.w;
    a[2] = cen.x; a[3] = cen.y; a[4] = cen.z; a[5] = cen.w;
    a[6] = nxt.x; a[7] = nxt.y;

    // coeff: wave-uniform address -> scalar loads
    float c0  = coeff[0],  c1  = coeff[1],  c2  = coeff[2],  c3  = coeff[3];
    float c4  = coeff[4],  c5  = coeff[5],  c6  = coeff[6],  c7  = coeff[7];
    float c8  = coeff[8],  c9  = coeff[9],  c10 = coeff[10], c11 = coeff[11];
    float c12 = coeff[12], c13 = coeff[13], c14 = coeff[14], c15 = coeff[15];
    float c16 = coeff[16], c17 = coeff[17];

    v4f ov;
    #pragma unroll
    for (int k = 0; k < 4; ++k) {
        float um2 = a[k];
        float um1 = a[k + 1];
        float uc  = a[k + 2];
        float up1 = a[k + 3];
        float up2 = a[k + 4];
        // feats @ coeff, factored Horner form (17 FMA + adds):
        float val = c0
            + um2 * (c1 + c6 * um2 + c11 * um1 + c15 * uc)
            + um1 * (c2 + c7 * um1 + c12 * uc  + c16 * up1)
            + uc  * (c3 + c8 * uc  + c13 * up1 + c17 * up2)
            + up1 * (c4 + c9 * up1 + c14 * up2)
            + up2 * (c5 + c10 * up2);
        ov[k] = val;
    }

    // nontemporal: out is write-once; keep L2 for u's overlapping re-reads
    __builtin_nontemporal_store(ov, out4 + v);
}

extern "C" void kernel_launch(void* const* d_in, const int* in_sizes, int n_in,
                              void* d_out, int out_size, void* d_ws, size_t ws_size,
                              hipStream_t stream) {
    // d_in[0] = t (int scalar, unused)
    const float* u     = (const float*)d_in[1];
    const float* coeff = (const float*)d_in[2];

    int total_vec = out_size / 4;             // 2,621,440
    int blocks    = total_vec / 256;          // 10,240 — exact, no remainder
    lorenz96_feats_kernel<<<blocks, 256, 0, stream>>>(
        (const float4*)u, coeff, (v4f*)d_out);
}